// Round 16
// baseline (216.581 us; speedup 1.0000x reference)
//
#include <hip/hip_runtime.h>

#define N 192
#define CCHUNK 8              // c columns per s1 block (B-frag reuse)
#define NCHUNK 28             // 224 / 8 chunks of c per db
#define XT 39                 // x-tile width per block (32 + CCHUNK - 1)
#define XP 41                 // x-tile LDS pitch (f32) - conflict spreading
#define NREP 8                // probe work multiplier

typedef __attribute__((ext_vector_type(8))) short short8;   // 8 bf16
typedef __attribute__((ext_vector_type(4))) float f32x4;

static __device__ __forceinline__ unsigned short f2bf(float x) {
    uint32_t u = __builtin_bit_cast(uint32_t, x);
    u += 0x7FFFu + ((u >> 16) & 1u);          // RNE (inputs finite)
    return (unsigned short)(u >> 16);
}

// ---------------------------------------------------------------------------
// prep: Abf[r][c] 384x384 packed (bf16 Ar, bf16 -Ai), zero pad row/col 383;
// Wt[dx][dy] packed (bf16 Wr, bf16 Wi); zero d_out (atomic target).
// amp = cos(atan2(rho,z))/R = z/(r2+z^2); ph = (2pi/0.5)*R.
// ---------------------------------------------------------------------------
__global__ __launch_bounds__(256) void prep_kernel(const float* __restrict__ fr,
                                                   const float* __restrict__ fi,
                                                   const float* __restrict__ zp,
                                                   uint32_t* __restrict__ Abf,
                                                   uint32_t* __restrict__ Wt,
                                                   float* __restrict__ out) {
    int idx = blockIdx.x * 256 + threadIdx.x;
    float z = zp[0];
    if (idx < 384 * 384) {
        int r = idx / 384, c = idx - r * 384;
        uint32_t pack = 0u;
        if (r < 383 && c < 383) {
            const float X0 = 191.00005f;      // 0.5*(2*192 + 1e-4) - 1
            float xr = (float)r - X0;
            float yc = (float)c - X0;
            float r2 = xr * xr + yc * yc;
            float R2 = r2 + z * z;
            float R  = sqrtf(R2);
            float amp = z / R2;
            float ph = 12.566371f * R;        // 2*pi/0.5
            float sv, cv;
            sincosf(ph, &sv, &cv);
            pack = (uint32_t)f2bf(amp * cv) | ((uint32_t)f2bf(-amp * sv) << 16);
        }
        Abf[idx] = pack;
    }
    if (idx < N * N) {
        int dy = idx / N, dx = idx - dy * N;
        Wt[dx * N + dy] = (uint32_t)f2bf(fr[idx]) | ((uint32_t)f2bf(fi[idx]) << 16);
        out[idx] = 0.f;                       // zero the atomic target each call
    }
}

// ---------------------------------------------------------------------------
// stage 1 body (r15 structure + B-loads moved AFTER the staging barrier so
// their live range is exactly the q-loop -> allocator should keep them in
// VGPRs; r11 probe showed VGPR_Count=64 -> B in scratch, K-loop serialized
// on scratch reloads). LOADB=false: constant B, asm-opaqued (no DCE) - probe
// isolates the B-load contribution.
// Accumulators split even/odd ks: 4 independent MFMA chains per wave.
// ---------------------------------------------------------------------------
template<bool LOADB>
static __device__ __forceinline__ void s1_body(const uint32_t* __restrict__ Abf,
                                               const uint32_t* __restrict__ Wt,
                                               float* __restrict__ out,
                                               int yoff) {
    __shared__ uint4 colAq[CCHUNK][384];      // 49.2 KB staged A columns
    __shared__ float outT[64 * XP];           // 10.5 KB per-block output tile

    const int tid = threadIdx.x;
    const int l   = tid & 63;
    const int w   = tid >> 6;                 // wave -> y-tile within third
    const int db  = blockIdx.x / NCHUNK;
    const int ck  = blockIdx.x - db * NCHUNK;
    const int ci0 = ck * CCHUNK;
    const int dx0 = db * 32;
    const int m   = l & 15;
    const int kg  = l >> 4;

    // zero the output tile
    for (int e = tid; e < 64 * XP; e += 256) outT[e] = 0.f;

    // stage all 8 columns as 16B quads (slot i = elems i..i+3 of Abf row c;
    // A symmetric: row c == column c). Slots >= 380 are never read.
    for (int i = tid; i < CCHUNK * 384; i += 256) {
        int j = i / 384, s = i - j * 384;
        uint4 v;
        __builtin_memcpy(&v, Abf + (dx0 + ci0 + j) * 384 + s, 16);
        colAq[j][s] = v;
    }
    __syncthreads();                          // barrier 1 of 2

    // B fragments: loaded AFTER the barrier (live range = q-loop only).
    uint4 bfr[2][12];
    #pragma unroll
    for (int t = 0; t < 2; ++t) {
        #pragma unroll
        for (int ks = 0; ks < 12; ++ks) {
            if constexpr (LOADB) {
                int dx = dx0 + t * 16 + m;
                bfr[t][ks] = *(const uint4*)(Wt + dx * N + ks * 16 + kg * 4);
            } else {
                bfr[t][ks] = make_uint4(0x3f803f80u, 0x3f803f80u,
                                        0x3f803f80u, 0x3f803f80u);
            }
            asm volatile("" : "+v"(bfr[t][ks].x), "+v"(bfr[t][ks].y),
                              "+v"(bfr[t][ks].z), "+v"(bfr[t][ks].w));
        }
    }

    const int srow = yoff + w * 16 + m;
    for (int q = 0; q < CCHUNK; ++q) {
        const int ci = ci0 + q;
        f32x4 a0e = {0.f,0.f,0.f,0.f}, a0o = {0.f,0.f,0.f,0.f};
        f32x4 a1e = {0.f,0.f,0.f,0.f}, a1o = {0.f,0.f,0.f,0.f};
        #pragma unroll
        for (int ks = 0; ks < 12; ks += 2) {
            int s0 = srow + ks * 16 + kg * 4;         // <= 363
            uint4 aq0 = colAq[q][s0];                 // one ds_read_b128
            uint4 aq1 = colAq[q][s0 + 16];            // <= 379
            union { uint4 q4; short8 v; } afe, afo, b0e, b1e, b0o, b1o;
            afe.q4 = aq0;          afo.q4 = aq1;
            b0e.q4 = bfr[0][ks];   b1e.q4 = bfr[1][ks];
            b0o.q4 = bfr[0][ks+1]; b1o.q4 = bfr[1][ks+1];
            a0e = __builtin_amdgcn_mfma_f32_16x16x32_bf16(afe.v, b0e.v, a0e, 0, 0, 0);
            a1e = __builtin_amdgcn_mfma_f32_16x16x32_bf16(afe.v, b1e.v, a1e, 0, 0, 0);
            a0o = __builtin_amdgcn_mfma_f32_16x16x32_bf16(afo.v, b0o.v, a0o, 0, 0, 0);
            a1o = __builtin_amdgcn_mfma_f32_16x16x32_bf16(afo.v, b1o.v, a1o, 0, 0, 0);
        }

        // fold: lane m holds dx0+m (acc0=e+o), dx0+16+m (acc1); x = c - dx
        // -> xt = (q+31) - m (acc0), (q+15) - m (acc1), all in [0, 39).
        // Rows disjoint per (w, kg) -> no races.
        if (ci < 223) {
            const int xb = q + 31;
            #pragma unroll
            for (int r = 0; r < 4; ++r) {
                int row = w * 16 + kg * 4 + r;
                outT[row * XP + xb - m]      += a0e[r] + a0o[r];
                outT[row * XP + xb - 16 - m] += a1e[r] + a1o[r];
            }
        }
    }
    __syncthreads();                          // barrier 2 of 2

    // flush: outT -> flipped out (global atomics)
    const int xg0 = ci0 - 31;
    for (int e = tid; e < 64 * XT; e += 256) {
        int row = e / XT, xt = e - row * XT;
        int x = xg0 + xt;
        if (x >= 0 && x < N) {
            int y = yoff + row;
            atomicAdd(&out[(191 - y) * N + (191 - x)], outT[row * XP + xt]);
        }
    }
}

__global__ __launch_bounds__(256, 2) void s1_kernel(const uint32_t* __restrict__ Abf,
                                                    const uint32_t* __restrict__ Wt,
                                                    float* __restrict__ out) {
    s1_body<true>(Abf, Wt, out, blockIdx.y * 64);
}

// PROBES (scratch only; dur deliberately sacrificial this round):
// probe_b = real B loads, probe_n = constant-B (no loads). 8 reps each.
__global__ __launch_bounds__(256, 2) void s1_probe_b(const uint32_t* __restrict__ Abf,
                                                     const uint32_t* __restrict__ Wt,
                                                     float* __restrict__ Pscr) {
    s1_body<true>(Abf, Wt, Pscr + (blockIdx.y / 3) * (N * N), (blockIdx.y % 3) * 64);
}

__global__ __launch_bounds__(256, 2) void s1_probe_n(const uint32_t* __restrict__ Abf,
                                                     const uint32_t* __restrict__ Wt,
                                                     float* __restrict__ Pscr) {
    s1_body<false>(Abf, Wt, Pscr + (blockIdx.y / 3) * (N * N), (blockIdx.y % 3) * 64);
}

extern "C" void kernel_launch(void* const* d_in, const int* in_sizes, int n_in,
                              void* d_out, int out_size, void* d_ws, size_t ws_size,
                              hipStream_t stream) {
    const float* fr = (const float*)d_in[0];
    const float* fi = (const float*)d_in[1];
    const float* zp = (const float*)d_in[2];

    uint32_t* Abf  = (uint32_t*)d_ws;                  // 384*384 u32 = 576 KB
    uint32_t* Wt   = Abf + 384 * 384;                  // 192*192 u32 = 144 KB
    float*    Pscr = (float*)(Wt + N * N);             // 8 * 36864 f32 = 1.2 MB
    // (probe planes accumulate garbage across replays - never read, harmless)

    prep_kernel<<<576, 256, 0, stream>>>(fr, fi, zp, Abf, Wt, (float*)d_out);
    s1_kernel<<<dim3(6 * NCHUNK, 3), 256, 0, stream>>>(Abf, Wt, (float*)d_out);
    s1_probe_b<<<dim3(6 * NCHUNK, 3 * NREP), 256, 0, stream>>>(Abf, Wt, Pscr);
    s1_probe_n<<<dim3(6 * NCHUNK, 3 * NREP), 256, 0, stream>>>(Abf, Wt, Pscr);
}

// Round 17
// 117.011 us; speedup vs baseline: 1.8509x; 1.8509x over previous
//
#include <hip/hip_runtime.h>

#define N 192
#define CCHUNK 8              // c columns per s1 block (B-frag reuse)
#define NCHUNK 28             // 224 / 8 chunks of c per db
#define XT 39                 // x-tile width per block (32 + CCHUNK - 1)
#define XP 41                 // x-tile LDS pitch (f32) - conflict spreading
#define NREP 8                // probe work multiplier

typedef __attribute__((ext_vector_type(8))) short short8;   // 8 bf16
typedef __attribute__((ext_vector_type(4))) float f32x4;

static __device__ __forceinline__ unsigned short f2bf(float x) {
    uint32_t u = __builtin_bit_cast(uint32_t, x);
    u += 0x7FFFu + ((u >> 16) & 1u);          // RNE (inputs finite)
    return (unsigned short)(u >> 16);
}

// ---------------------------------------------------------------------------
// prep: Abf[r][c] 384x384 packed (bf16 Ar, bf16 -Ai), zero pad row/col 383;
// Wt[dx][dy] packed (bf16 Wr, bf16 Wi); zero d_out (atomic target).
// amp = cos(atan2(rho,z))/R = z/(r2+z^2); ph = (2pi/0.5)*R.
// ---------------------------------------------------------------------------
__global__ __launch_bounds__(256) void prep_kernel(const float* __restrict__ fr,
                                                   const float* __restrict__ fi,
                                                   const float* __restrict__ zp,
                                                   uint32_t* __restrict__ Abf,
                                                   uint32_t* __restrict__ Wt,
                                                   float* __restrict__ out) {
    int idx = blockIdx.x * 256 + threadIdx.x;
    float z = zp[0];
    if (idx < 384 * 384) {
        int r = idx / 384, c = idx - r * 384;
        uint32_t pack = 0u;
        if (r < 383 && c < 383) {
            const float X0 = 191.00005f;      // 0.5*(2*192 + 1e-4) - 1
            float xr = (float)r - X0;
            float yc = (float)c - X0;
            float r2 = xr * xr + yc * yc;
            float R2 = r2 + z * z;
            float R  = sqrtf(R2);
            float amp = z / R2;
            float ph = 12.566371f * R;        // 2*pi/0.5
            float sv, cv;
            sincosf(ph, &sv, &cv);
            pack = (uint32_t)f2bf(amp * cv) | ((uint32_t)f2bf(-amp * sv) << 16);
        }
        Abf[idx] = pack;
    }
    if (idx < N * N) {
        int dy = idx / N, dx = idx - dy * N;
        Wt[dx * N + dy] = (uint32_t)f2bf(fr[idx]) | ((uint32_t)f2bf(fi[idx]) << 16);
        out[idx] = 0.f;                       // zero the atomic target each call
    }
}

// ---------------------------------------------------------------------------
// stage 1 body — ROUND-17 STRUCTURE: ks-OUTER / q-INNER.
//   G[c][y][dx] = sum_dy Ar[y+dy][c]*Wr[dy][dx] - Ai[..]*Wi[..]
// 16 persistent accumulators acc{0,1}[8] (MFMA C/D -> AGPR path, allocator
// keeps these); only TWO B fragments live at a time (1-deep prefetch).
// r11/r16 proved the old q-outer loop spilled B (VGPR=64/88 < 96 needed) and
// serialized on scratch reloads. A staged as uint2 pairs (r5-r7 layout,
// 2x ds_read_b64); dx-contraction folded after the ks-loop into LDS tile
// outT[64][39] (x = c - dx), flushed with atomicAdd into flipped out.
// Block = (db, chunk of 8 c's, y-third of 64 rows), 4 waves = 4 y-tiles.
// LDS 24.6 + 10.5 = 35.1 KB -> 4 blocks/CU; est ~110 VGPR, cap 170.
// ---------------------------------------------------------------------------
static __device__ __forceinline__ void s1_body(const uint32_t* __restrict__ Abf,
                                               const uint32_t* __restrict__ Wt,
                                               float* __restrict__ out,
                                               int yoff) {
    __shared__ uint2 colAd[CCHUNK][384];      // 24.6 KB staged A columns (pairs)
    __shared__ float outT[64 * XP];           // 10.5 KB per-block output tile

    const int tid = threadIdx.x;
    const int l   = tid & 63;
    const int w   = tid >> 6;                 // wave -> y-tile within third
    const int db  = blockIdx.x / NCHUNK;
    const int ck  = blockIdx.x - db * NCHUNK;
    const int ci0 = ck * CCHUNK;
    const int dx0 = db * 32;
    const int m   = l & 15;
    const int kg  = l >> 4;

    // zero the output tile
    for (int e = tid; e < 64 * XP; e += 256) outT[e] = 0.f;

    // stage 8 columns as duplicated pairs: colAd[j][s] = (elem s, elem s+1)
    // of Abf row (dx0+ci0+j); A symmetric: row c == column c. s in [0,383).
    for (int i = tid; i < CCHUNK * 383; i += 256) {
        int j = i / 383, s = i - j * 383;
        const uint32_t* ar = Abf + (dx0 + ci0 + j) * 384;
        uint32_t v0 = ar[s];
        uint32_t v1 = (s < 382) ? ar[s + 1] : 0u;
        colAd[j][s] = make_uint2(v0, v1);
    }
    __syncthreads();                          // barrier 1 of 2

    const int srow = yoff + w * 16 + m;
    f32x4 acc0[CCHUNK], acc1[CCHUNK];
    #pragma unroll
    for (int q = 0; q < CCHUNK; ++q) {
        acc0[q] = (f32x4){0.f, 0.f, 0.f, 0.f};
        acc1[q] = (f32x4){0.f, 0.f, 0.f, 0.f};
    }

    // B row pointers for this lane's two dx values (k-slice kg*4, step 16/ks)
    const uint32_t* w0p = Wt + (dx0 + m) * N + kg * 4;
    const uint32_t* w1p = Wt + (dx0 + 16 + m) * N + kg * 4;

    union BU { uint4 q4; short8 v; };
    BU b0c, b1c, b0n, b1n;
    b0c.q4 = *(const uint4*)(w0p);
    b1c.q4 = *(const uint4*)(w1p);

    #pragma unroll 1   // keep the loop rolled: only 2 B frags live at a time
    for (int ks = 0; ks < 12; ++ks) {
        if (ks < 11) {                        // prefetch next B pair
            b0n.q4 = *(const uint4*)(w0p + (ks + 1) * 16);
            b1n.q4 = *(const uint4*)(w1p + (ks + 1) * 16);
        }
        const int s = srow + ks * 16 + kg * 4;          // <= 379
        #pragma unroll
        for (int q = 0; q < CCHUNK; ++q) {
            uint2 a0 = colAd[q][s];                     // elems s, s+1
            uint2 a1 = colAd[q][s + 2];                 // elems s+2, s+3
            union { uint32_t u[4]; short8 v; } af;
            af.u[0] = a0.x; af.u[1] = a0.y; af.u[2] = a1.x; af.u[3] = a1.y;
            acc0[q] = __builtin_amdgcn_mfma_f32_16x16x32_bf16(af.v, b0c.v, acc0[q], 0, 0, 0);
            acc1[q] = __builtin_amdgcn_mfma_f32_16x16x32_bf16(af.v, b1c.v, acc1[q], 0, 0, 0);
        }
        b0c = b0n; b1c = b1n;
    }

    // fold all q: lane m holds dx0+m (acc0), dx0+16+m (acc1); x = c - dx
    // -> xt = (q+31) - m (acc0), (q+15) - m (acc1), all in [0, 39).
    // Rows disjoint per (w, kg) -> wave-private, no barrier needed.
    #pragma unroll
    for (int q = 0; q < CCHUNK; ++q) {
        if (ci0 + q < 223) {
            const int xb = q + 31;
            #pragma unroll
            for (int r = 0; r < 4; ++r) {
                int row = w * 16 + kg * 4 + r;
                outT[row * XP + xb - m]      += acc0[q][r];
                outT[row * XP + xb - 16 - m] += acc1[q][r];
            }
        }
    }
    __syncthreads();                          // barrier 2 of 2

    // flush: outT -> flipped out (global atomics)
    const int xg0 = ci0 - 31;
    for (int e = tid; e < 64 * XT; e += 256) {
        int row = e / XT, xt = e - row * XT;
        int x = xg0 + xt;
        if (x >= 0 && x < N) {
            int y = yoff + row;
            atomicAdd(&out[(191 - y) * N + (191 - x)], outT[row * XP + xt]);
        }
    }
}

__global__ __launch_bounds__(256, 3) void s1_kernel(const uint32_t* __restrict__ Abf,
                                                    const uint32_t* __restrict__ Wt,
                                                    float* __restrict__ out) {
    s1_body(Abf, Wt, out, blockIdx.y * 64);
}

// PROBE: 8 reps into scratch planes (accumulate garbage across replays -
// never read; same atomic pattern). Gives the counter row for s1.
__global__ __launch_bounds__(256, 3) void s1_probe(const uint32_t* __restrict__ Abf,
                                                   const uint32_t* __restrict__ Wt,
                                                   float* __restrict__ Pscr) {
    s1_body(Abf, Wt, Pscr + (blockIdx.y / 3) * (N * N), (blockIdx.y % 3) * 64);
}

extern "C" void kernel_launch(void* const* d_in, const int* in_sizes, int n_in,
                              void* d_out, int out_size, void* d_ws, size_t ws_size,
                              hipStream_t stream) {
    const float* fr = (const float*)d_in[0];
    const float* fi = (const float*)d_in[1];
    const float* zp = (const float*)d_in[2];

    uint32_t* Abf  = (uint32_t*)d_ws;                  // 384*384 u32 = 576 KB
    uint32_t* Wt   = Abf + 384 * 384;                  // 192*192 u32 = 144 KB
    float*    Pscr = (float*)(Wt + N * N);             // 8 * 36864 f32 = 1.2 MB

    prep_kernel<<<576, 256, 0, stream>>>(fr, fi, zp, Abf, Wt, (float*)d_out);
    s1_kernel<<<dim3(6 * NCHUNK, 3), 256, 0, stream>>>(Abf, Wt, (float*)d_out);
    s1_probe<<<dim3(6 * NCHUNK, 3 * NREP), 256, 0, stream>>>(Abf, Wt, Pscr);
}

// Round 18
// 27.784 us; speedup vs baseline: 7.7952x; 4.2115x over previous
//
#include <hip/hip_runtime.h>

#define N 192
#define CCHUNK 8              // c columns per s1 block (B-frag reuse)
#define NCHUNK 28             // 224 / 8 chunks of c per db
#define XT 39                 // x-tile width per block (32 + CCHUNK - 1)
#define XP 41                 // x-tile LDS pitch (f32) - conflict spreading

typedef __attribute__((ext_vector_type(8))) short short8;   // 8 bf16
typedef __attribute__((ext_vector_type(4))) float f32x4;

static __device__ __forceinline__ unsigned short f2bf(float x) {
    uint32_t u = __builtin_bit_cast(uint32_t, x);
    u += 0x7FFFu + ((u >> 16) & 1u);          // RNE (inputs finite)
    return (unsigned short)(u >> 16);
}

// ---------------------------------------------------------------------------
// prep: Abf[r][c] 384x384 packed (bf16 Ar, bf16 -Ai), zero pad row/col 383;
// Wt[dx][dy] packed (bf16 Wr, bf16 Wi); zero d_out (atomic target).
// amp = cos(atan2(rho,z))/R = z/(r2+z^2); ph = (2pi/0.5)*R.
// ---------------------------------------------------------------------------
__global__ __launch_bounds__(256) void prep_kernel(const float* __restrict__ fr,
                                                   const float* __restrict__ fi,
                                                   const float* __restrict__ zp,
                                                   uint32_t* __restrict__ Abf,
                                                   uint32_t* __restrict__ Wt,
                                                   float* __restrict__ out) {
    int idx = blockIdx.x * 256 + threadIdx.x;
    float z = zp[0];
    if (idx < 384 * 384) {
        int r = idx / 384, c = idx - r * 384;
        uint32_t pack = 0u;
        if (r < 383 && c < 383) {
            const float X0 = 191.00005f;      // 0.5*(2*192 + 1e-4) - 1
            float xr = (float)r - X0;
            float yc = (float)c - X0;
            float r2 = xr * xr + yc * yc;
            float R2 = r2 + z * z;
            float R  = sqrtf(R2);
            float amp = z / R2;
            float ph = 12.566371f * R;        // 2*pi/0.5
            float sv, cv;
            sincosf(ph, &sv, &cv);
            pack = (uint32_t)f2bf(amp * cv) | ((uint32_t)f2bf(-amp * sv) << 16);
        }
        Abf[idx] = pack;
    }
    if (idx < N * N) {
        int dy = idx / N, dx = idx - dy * N;
        Wt[dx * N + dy] = (uint32_t)f2bf(fr[idx]) | ((uint32_t)f2bf(fi[idx]) << 16);
        out[idx] = 0.f;                       // zero the atomic target each call
    }
}

// ---------------------------------------------------------------------------
// stage 1 — ks-OUTER / q-INNER (r17 structure, probe-verified 12.6 us/rep)
// + ROUND-18 DELTA: B prefetch depth 1 -> 3 (rotating 3-buffer, static
// indices). r17 counters showed all pipes <30% busy at 40% occupancy ->
// latency-bound; depth-1 prefetch left every ks-iter stalled on L2 (~200-500
// cy) with only ~170 cy of covering work. Depth 3 covers ~510 cy.
//   G[c][y][dx] = sum_dy Ar[y+dy][c]*Wr[dy][dx] - Ai[..]*Wi[..]
// 16 persistent accumulators (AGPR side, r17 proof: VGPR=52, no spill);
// A staged as duplicated uint2 pairs; dx-contraction folded into LDS tile
// outT[64][39] (x = c - dx); atomicAdd flush into flipped out.
// Block = (db, chunk of 8 c's, y-third of 64 rows), 4 waves = 4 y-tiles.
// LDS 24.6 + 10.5 = 35.1 KB -> 4 blocks/CU.
// ---------------------------------------------------------------------------
__global__ __launch_bounds__(256, 3) void s1_kernel(const uint32_t* __restrict__ Abf,
                                                    const uint32_t* __restrict__ Wt,
                                                    float* __restrict__ out) {
    __shared__ uint2 colAd[CCHUNK][384];      // 24.6 KB staged A columns (pairs)
    __shared__ float outT[64 * XP];           // 10.5 KB per-block output tile

    const int tid  = threadIdx.x;
    const int l    = tid & 63;
    const int w    = tid >> 6;                // wave -> y-tile within third
    const int db   = blockIdx.x / NCHUNK;
    const int ck   = blockIdx.x - db * NCHUNK;
    const int ci0  = ck * CCHUNK;
    const int dx0  = db * 32;
    const int yoff = blockIdx.y * 64;
    const int m    = l & 15;
    const int kg   = l >> 4;

    // zero the output tile
    for (int e = tid; e < 64 * XP; e += 256) outT[e] = 0.f;

    // stage 8 columns as duplicated pairs: colAd[j][s] = (elem s, elem s+1)
    // of Abf row (dx0+ci0+j); A symmetric: row c == column c. s in [0,383).
    for (int i = tid; i < CCHUNK * 383; i += 256) {
        int j = i / 383, s = i - j * 383;
        const uint32_t* ar = Abf + (dx0 + ci0 + j) * 384;
        uint32_t v0 = ar[s];
        uint32_t v1 = (s < 382) ? ar[s + 1] : 0u;
        colAd[j][s] = make_uint2(v0, v1);
    }
    __syncthreads();                          // barrier 1 of 2

    const int srow = yoff + w * 16 + m;
    f32x4 acc0[CCHUNK], acc1[CCHUNK];
    #pragma unroll
    for (int q = 0; q < CCHUNK; ++q) {
        acc0[q] = (f32x4){0.f, 0.f, 0.f, 0.f};
        acc1[q] = (f32x4){0.f, 0.f, 0.f, 0.f};
    }

    // B row pointers for this lane's two dx values (k-slice kg*4, step 16/ks)
    const uint32_t* w0p = Wt + (dx0 + m) * N + kg * 4;
    const uint32_t* w1p = Wt + (dx0 + 16 + m) * N + kg * 4;

    union BU { uint4 q4; short8 v; };
    BU b0[3], b1[3];                          // rotating 3-deep prefetch
    #pragma unroll
    for (int i = 0; i < 3; ++i) {
        b0[i].q4 = *(const uint4*)(w0p + i * 16);
        b1[i].q4 = *(const uint4*)(w1p + i * 16);
    }

    #pragma unroll 1   // strip of 3 static sub-steps; 6 B loads in flight
    for (int ks = 0; ks < 12; ks += 3) {
        #pragma unroll
        for (int h = 0; h < 3; ++h) {
            const int kk = ks + h;
            const int s  = srow + kk * 16 + kg * 4;   // <= 379
            #pragma unroll
            for (int q = 0; q < CCHUNK; ++q) {
                uint2 a0 = colAd[q][s];               // elems s, s+1
                uint2 a1 = colAd[q][s + 2];           // elems s+2, s+3
                union { uint32_t u[4]; short8 v; } af;
                af.u[0] = a0.x; af.u[1] = a0.y; af.u[2] = a1.x; af.u[3] = a1.y;
                acc0[q] = __builtin_amdgcn_mfma_f32_16x16x32_bf16(af.v, b0[h].v, acc0[q], 0, 0, 0);
                acc1[q] = __builtin_amdgcn_mfma_f32_16x16x32_bf16(af.v, b1[h].v, acc1[q], 0, 0, 0);
            }
            if (kk + 3 < 12) {                // refill slot h, 3 steps ahead
                b0[h].q4 = *(const uint4*)(w0p + (kk + 3) * 16);
                b1[h].q4 = *(const uint4*)(w1p + (kk + 3) * 16);
            }
        }
    }

    // fold all q: lane m holds dx0+m (acc0), dx0+16+m (acc1); x = c - dx
    // -> xt = (q+31) - m (acc0), (q+15) - m (acc1), all in [0, 39).
    // Rows disjoint per (w, kg) -> wave-private.
    #pragma unroll
    for (int q = 0; q < CCHUNK; ++q) {
        if (ci0 + q < 223) {
            const int xb = q + 31;
            #pragma unroll
            for (int r = 0; r < 4; ++r) {
                int row = w * 16 + kg * 4 + r;
                outT[row * XP + xb - m]      += acc0[q][r];
                outT[row * XP + xb - 16 - m] += acc1[q][r];
            }
        }
    }
    __syncthreads();                          // barrier 2 of 2

    // flush: outT -> flipped d_out (global atomics)
    const int xg0 = ci0 - 31;
    for (int e = tid; e < 64 * XT; e += 256) {
        int row = e / XT, xt = e - row * XT;
        int x = xg0 + xt;
        if (x >= 0 && x < N) {
            int y = yoff + row;
            atomicAdd(&out[(191 - y) * N + (191 - x)], outT[row * XP + xt]);
        }
    }
}

extern "C" void kernel_launch(void* const* d_in, const int* in_sizes, int n_in,
                              void* d_out, int out_size, void* d_ws, size_t ws_size,
                              hipStream_t stream) {
    const float* fr = (const float*)d_in[0];
    const float* fi = (const float*)d_in[1];
    const float* zp = (const float*)d_in[2];

    uint32_t* Abf = (uint32_t*)d_ws;                   // 384*384 u32 = 576 KB
    uint32_t* Wt  = Abf + 384 * 384;                   // 192*192 u32 = 144 KB

    prep_kernel<<<576, 256, 0, stream>>>(fr, fi, zp, Abf, Wt, (float*)d_out);
    s1_kernel<<<dim3(6 * NCHUNK, 3), 256, 0, stream>>>(Abf, Wt, (float*)d_out);
}